// Round 6
// baseline (142.888 us; speedup 1.0000x reference)
//
#include <hip/hip_runtime.h>

#define T_STEPS 20
#define NI 5
#define NH 100
#define NO 3

// One thread per batch element; h outer, t inner (fully unrolled, inline asm).
//
// Regime (R3/R4): pure VALU-issue bound at the power-limited sustained clock
// (~1.55 GHz; SMEM-prefetch discriminator was null). Lever: VALU count.
//
// R6 = R5's exec-mask predication with the ORDER BUG fixed (R5 applied the
// reset before the decay; reference subtracts reset after decay+drive).
// Per time step t (one masked region, mask = spike_{t-1}):
//   v_mul / v_add                (full exec)  tmp = fl(fl(0.95*mem)+c)
//   s_mov exec, mask_{t-1}
//     v_add mem, -1.0, mem       reset: fl(tmp-1) spiked / fl(tmp-0) else
//     v_add A*[t-1], w*, A*      == fmac with spf in {0,1}, bit-exact
//   s_mov exec, full
//   v_cmp_lt_f32 mask_t, 1.0, mem
// 7 VALU + 2 SALU per t (was 8 VALU). Each asm block restores EXEC, so
// compiler-scheduled code between blocks never runs masked.
//
// Exactness: spike/reset predicate (mem > 1) == (fl(mem-1) > 0) in fp32
// (Sterbenz); masked -1.0 add == the reference's separate v_sub by spf;
// masked acc add == fmac by 0/1 (acc can never be -0: fp32 adds from +0
// starts never yield -0); ascending-h accumulation order preserved.
__global__ __launch_bounds__(256, 2) void snn_kernel(
    const float* __restrict__ x,
    const float* __restrict__ W1,
    const float* __restrict__ b1,
    const float* __restrict__ W2,
    const float* __restrict__ b2,
    float* __restrict__ out, int B)
{
    int b = blockIdx.x * blockDim.x + threadIdx.x;
    if (b >= B) return;

    // True active-lane set (save/restore target for masked regions).
    const unsigned long long full = __builtin_amdgcn_read_exec();

    float xv[NI];
#pragma unroll
    for (int i = 0; i < NI; ++i) xv[i] = x[b * NI + i];

    float acc[T_STEPS][NO];
#pragma unroll
    for (int t = 0; t < T_STEPS; ++t)
#pragma unroll
        for (int o = 0; o < NO; ++o) acc[t][o] = 0.0f;

#pragma unroll 2
    for (int h = 0; h < NH; ++h) {
        // cur1[b,h] = x[b,:] . W1[h,:] + b1[h]   (wave-uniform W1/b1 -> s_load)
        float c = b1[h];
#pragma unroll
        for (int i = 0; i < NI; ++i) c = __builtin_fmaf(xv[i], W1[h * NI + i], c);

        float w0 = W2[0 * NH + h];
        float w1 = W2[1 * NH + h];
        float w2 = W2[2 * NH + h];

        float mem;
        unsigned long long mprev, mnext;

        // t = 0: mem0 == c exactly (0.95*0=0, 0+c=c, c-0=c all exact).
        asm volatile(
            "v_cmp_lt_f32 %[mk], 1.0, %[c]"
            : [mk] "=s"(mprev)
            : [c] "v"(c));

        // t = 1: mul reads c directly (no mem mov). Masked region applies
        // spike_0's reset (after decay+drive) and acc[0] adds.
        asm volatile(
            "v_mul_f32 %[mem], 0x3F733333, %[c]\n\t"
            "v_add_f32 %[mem], %[mem], %[c]\n\t"
            "s_mov_b64 exec, %[pm]\n\t"
            "v_add_f32 %[mem], -1.0, %[mem]\n\t"
            "v_add_f32 %[A0], %[w0], %[A0]\n\t"
            "v_add_f32 %[A1], %[w1], %[A1]\n\t"
            "v_add_f32 %[A2], %[w2], %[A2]\n\t"
            "s_mov_b64 exec, %[fl]\n\t"
            "v_cmp_lt_f32 %[nm], 1.0, %[mem]"
            : [mem] "=&v"(mem), [nm] "=s"(mnext),
              [A0] "+v"(acc[0][0]), [A1] "+v"(acc[0][1]), [A2] "+v"(acc[0][2])
            : [pm] "s"(mprev), [fl] "s"(full), [c] "v"(c),
              [w0] "s"(w0), [w1] "s"(w1), [w2] "s"(w2));
        mprev = mnext;

        // t = 2..19: steady-state 7-VALU step.
#pragma unroll
        for (int t = 2; t < T_STEPS; ++t) {
            asm volatile(
                "v_mul_f32 %[mem], 0x3F733333, %[mem]\n\t"
                "v_add_f32 %[mem], %[mem], %[c]\n\t"
                "s_mov_b64 exec, %[pm]\n\t"
                "v_add_f32 %[mem], -1.0, %[mem]\n\t"
                "v_add_f32 %[A0], %[w0], %[A0]\n\t"
                "v_add_f32 %[A1], %[w1], %[A1]\n\t"
                "v_add_f32 %[A2], %[w2], %[A2]\n\t"
                "s_mov_b64 exec, %[fl]\n\t"
                "v_cmp_lt_f32 %[nm], 1.0, %[mem]"
                : [mem] "+v"(mem), [nm] "=s"(mnext),
                  [A0] "+v"(acc[t - 1][0]), [A1] "+v"(acc[t - 1][1]),
                  [A2] "+v"(acc[t - 1][2])
                : [pm] "s"(mprev), [fl] "s"(full), [c] "v"(c),
                  [w0] "s"(w0), [w1] "s"(w1), [w2] "s"(w2));
            mprev = mnext;
        }

        // Epilogue: acc adds for the t=19 spike (no further reset needed).
        asm volatile(
            "s_mov_b64 exec, %[pm]\n\t"
            "v_add_f32 %[A0], %[w0], %[A0]\n\t"
            "v_add_f32 %[A1], %[w1], %[A1]\n\t"
            "v_add_f32 %[A2], %[w2], %[A2]\n\t"
            "s_mov_b64 exec, %[fl]"
            : [A0] "+v"(acc[T_STEPS - 1][0]), [A1] "+v"(acc[T_STEPS - 1][1]),
              [A2] "+v"(acc[T_STEPS - 1][2])
            : [pm] "s"(mprev), [fl] "s"(full),
              [w0] "s"(w0), [w1] "s"(w1), [w2] "s"(w2));
    }

    // Layer-2 LIF dynamics + spike count (~1% of runtime, plain C)
    float m2[NO]  = {0.0f, 0.0f, 0.0f};
    float cnt[NO] = {0.0f, 0.0f, 0.0f};
    float r2f[NO] = {0.0f, 0.0f, 0.0f};
#pragma unroll
    for (int t = 0; t < T_STEPS; ++t) {
#pragma unroll
        for (int o = 0; o < NO; ++o) {
            float cur = __fadd_rn(acc[t][o], b2[o]);   // (sum) + b2, ref order
            float tmp2 = __fmul_rn(0.95f, m2[o]);
            tmp2 = __fadd_rn(tmp2, cur);
            m2[o] = __fsub_rn(tmp2, r2f[o]);
            r2f[o] = (m2[o] > 1.0f) ? 1.0f : 0.0f;
            cnt[o] = __fadd_rn(cnt[o], r2f[o]);
        }
    }
#pragma unroll
    for (int o = 0; o < NO; ++o) out[b * NO + o] = cnt[o];
}

extern "C" void kernel_launch(void* const* d_in, const int* in_sizes, int n_in,
                              void* d_out, int out_size, void* d_ws, size_t ws_size,
                              hipStream_t stream) {
    const float* x  = (const float*)d_in[0];
    const float* W1 = (const float*)d_in[1];
    const float* b1 = (const float*)d_in[2];
    const float* W2 = (const float*)d_in[3];
    const float* b2 = (const float*)d_in[4];
    float* out = (float*)d_out;

    int B = in_sizes[0] / NI;  // 262144
    int threads = 256;
    int blocks = (B + threads - 1) / threads;
    snn_kernel<<<blocks, threads, 0, stream>>>(x, W1, b1, W2, b2, out, B);
}

// Round 7
// 136.787 us; speedup vs baseline: 1.0446x; 1.0446x over previous
//
#include <hip/hip_runtime.h>

#define T_STEPS 20
#define NI 5
#define NH 100
#define NO 3

// One thread per batch element; h outer, t inner (fully unrolled, inline asm).
//
// FINAL FORM (R7 = R4 revert). Established regime: pure VALU-issue bound at
// the power-limited sustained clock (~1.55 GHz = m07's 65%-of-nominal dense
// VALU plateau). Discriminators run:
//  - R4: 2-deep SMEM software pipeline of weight loads -> null (no bubbles).
//  - R6: exec-mask predication (7 VALU + 2 SALU/t) -> -12% instructions but
//    +1% time; VALUBusy 130->108 (SALU-writes-EXEC hazard stalls). Reverted.
//  - pk_f32 packing: CDNA4 scalar fp32 is full-rate (157.3 TF spec, m07
//    103 TF measured scalar); v_pk_*_f32 issues at half rate -> no win. Dropped.
// 8-op/(h,t) cndmask form = measured optimum, ~98% of the issue-model
// ceiling (4 waves/SIMD x 16.5k instr x 2 cyc / 1.55 GHz = 85 us; meas 87).
//
// Exactness: mem recurrence via separate v_mul/v_add/v_sub (matches the
// reference's non-contracted fp32 rounding); spike cmp is (1.0 < mem);
// acc fmacs are exact (spf in {0,1}) in ascending-h order. t=0/t=1 peeled
// (mem0 == c exactly; t=1 mul reads c directly).
__device__ __forceinline__ void lif_unit(float c, float w0, float w1, float w2,
                                         float one, float (&acc)[T_STEPS][NO])
{
    float mem, spf, tmp;

    // t = 0: mem0 == c exactly (0.95*0=0, 0+c=c, c-0=c, all exact).
    asm volatile(
        "v_cmp_lt_f32 vcc, 1.0, %[c]\n\t"
        "v_cndmask_b32 %[spf], 0, %[one], vcc\n\t"
        "v_fmac_f32 %[A0], %[w0], %[spf]\n\t"
        "v_fmac_f32 %[A1], %[w1], %[spf]\n\t"
        "v_fmac_f32 %[A2], %[w2], %[spf]"
        : [spf] "=&v"(spf),
          [A0] "+v"(acc[0][0]), [A1] "+v"(acc[0][1]), [A2] "+v"(acc[0][2])
        : [c] "v"(c), [one] "v"(one),
          [w0] "s"(w0), [w1] "s"(w1), [w2] "s"(w2)
        : "vcc");

    // t = 1: mul reads c directly (mem register not yet needed).
    asm volatile(
        "v_mul_f32 %[tmp], 0x3F733333, %[c]\n\t"
        "v_add_f32 %[tmp], %[tmp], %[c]\n\t"
        "v_sub_f32 %[mem], %[tmp], %[spf]\n\t"
        "v_cmp_lt_f32 vcc, 1.0, %[mem]\n\t"
        "v_cndmask_b32 %[spf], 0, %[one], vcc\n\t"
        "v_fmac_f32 %[A0], %[w0], %[spf]\n\t"
        "v_fmac_f32 %[A1], %[w1], %[spf]\n\t"
        "v_fmac_f32 %[A2], %[w2], %[spf]"
        : [tmp] "=&v"(tmp), [mem] "=&v"(mem), [spf] "+v"(spf),
          [A0] "+v"(acc[1][0]), [A1] "+v"(acc[1][1]), [A2] "+v"(acc[1][2])
        : [c] "v"(c), [one] "v"(one),
          [w0] "s"(w0), [w1] "s"(w1), [w2] "s"(w2)
        : "vcc");

    // t = 2..19: steady-state 8-op step.
#pragma unroll
    for (int t = 2; t < T_STEPS; ++t) {
        asm volatile(
            "v_mul_f32 %[tmp], 0x3F733333, %[mem]\n\t"
            "v_add_f32 %[tmp], %[tmp], %[c]\n\t"
            "v_sub_f32 %[mem], %[tmp], %[spf]\n\t"
            "v_cmp_lt_f32 vcc, 1.0, %[mem]\n\t"
            "v_cndmask_b32 %[spf], 0, %[one], vcc\n\t"
            "v_fmac_f32 %[A0], %[w0], %[spf]\n\t"
            "v_fmac_f32 %[A1], %[w1], %[spf]\n\t"
            "v_fmac_f32 %[A2], %[w2], %[spf]"
            : [tmp] "=&v"(tmp), [mem] "+v"(mem), [spf] "+v"(spf),
              [A0] "+v"(acc[t][0]), [A1] "+v"(acc[t][1]), [A2] "+v"(acc[t][2])
            : [c] "v"(c), [one] "v"(one),
              [w0] "s"(w0), [w1] "s"(w1), [w2] "s"(w2)
            : "vcc");
    }
}

__global__ __launch_bounds__(256, 2) void snn_kernel(
    const float* __restrict__ x,
    const float* __restrict__ W1,
    const float* __restrict__ b1,
    const float* __restrict__ W2,
    const float* __restrict__ b2,
    float* __restrict__ out, int B)
{
    int b = blockIdx.x * blockDim.x + threadIdx.x;
    if (b >= B) return;

    float xv[NI];
#pragma unroll
    for (int i = 0; i < NI; ++i) xv[i] = x[b * NI + i];

    float acc[T_STEPS][NO];
#pragma unroll
    for (int t = 0; t < T_STEPS; ++t)
#pragma unroll
        for (int o = 0; o < NO; ++o) acc[t][o] = 0.0f;

    const float one = 1.0f;

    // Software pipeline: weights for units (h, h+1) resident in "cur" slots;
    // (h+2, h+3) prefetched into "nxt" slots before compute consumes cur.
    // All wave-uniform -> SGPRs; rotation is s_mov (scalar pipe, free).
    float cb0 = b1[0], cb1 = b1[1];
    float cW1a[NI], cW1b[NI];
#pragma unroll
    for (int i = 0; i < NI; ++i) { cW1a[i] = W1[i]; cW1b[i] = W1[NI + i]; }
    float cw2a0 = W2[0 * NH + 0], cw2a1 = W2[1 * NH + 0], cw2a2 = W2[2 * NH + 0];
    float cw2b0 = W2[0 * NH + 1], cw2b1 = W2[1 * NH + 1], cw2b2 = W2[2 * NH + 1];

    for (int h = 0; h < NH; h += 2) {
        const int hn = (h + 2 < NH) ? (h + 2) : 0;  // wrap: harmless reload

        // Prefetch next pair's weights NOW; their s_waitcnt lands ~330
        // instructions later (after both lif_units below).
        float nb0 = b1[hn], nb1 = b1[hn + 1];
        float nW1a[NI], nW1b[NI];
#pragma unroll
        for (int i = 0; i < NI; ++i) {
            nW1a[i] = W1[hn * NI + i];
            nW1b[i] = W1[(hn + 1) * NI + i];
        }
        float nw2a0 = W2[0 * NH + hn],     nw2a1 = W2[1 * NH + hn],     nw2a2 = W2[2 * NH + hn];
        float nw2b0 = W2[0 * NH + hn + 1], nw2b1 = W2[1 * NH + hn + 1], nw2b2 = W2[2 * NH + hn + 1];

        // Unit h
        float c0 = cb0;
#pragma unroll
        for (int i = 0; i < NI; ++i) c0 = __builtin_fmaf(xv[i], cW1a[i], c0);
        lif_unit(c0, cw2a0, cw2a1, cw2a2, one, acc);

        // Unit h+1
        float c1 = cb1;
#pragma unroll
        for (int i = 0; i < NI; ++i) c1 = __builtin_fmaf(xv[i], cW1b[i], c1);
        lif_unit(c1, cw2b0, cw2b1, cw2b2, one, acc);

        // Rotate prefetched -> current (scalar moves)
        cb0 = nb0; cb1 = nb1;
#pragma unroll
        for (int i = 0; i < NI; ++i) { cW1a[i] = nW1a[i]; cW1b[i] = nW1b[i]; }
        cw2a0 = nw2a0; cw2a1 = nw2a1; cw2a2 = nw2a2;
        cw2b0 = nw2b0; cw2b1 = nw2b1; cw2b2 = nw2b2;
    }

    // Layer-2 LIF dynamics + spike count (~1% of runtime, plain C)
    float m2[NO]  = {0.0f, 0.0f, 0.0f};
    float cnt[NO] = {0.0f, 0.0f, 0.0f};
    float r2f[NO] = {0.0f, 0.0f, 0.0f};
#pragma unroll
    for (int t = 0; t < T_STEPS; ++t) {
#pragma unroll
        for (int o = 0; o < NO; ++o) {
            float cur = __fadd_rn(acc[t][o], b2[o]);   // (sum) + b2, ref order
            float tmp2 = __fmul_rn(0.95f, m2[o]);
            tmp2 = __fadd_rn(tmp2, cur);
            m2[o] = __fsub_rn(tmp2, r2f[o]);
            r2f[o] = (m2[o] > 1.0f) ? 1.0f : 0.0f;
            cnt[o] = __fadd_rn(cnt[o], r2f[o]);
        }
    }
#pragma unroll
    for (int o = 0; o < NO; ++o) out[b * NO + o] = cnt[o];
}

extern "C" void kernel_launch(void* const* d_in, const int* in_sizes, int n_in,
                              void* d_out, int out_size, void* d_ws, size_t ws_size,
                              hipStream_t stream) {
    const float* x  = (const float*)d_in[0];
    const float* W1 = (const float*)d_in[1];
    const float* b1 = (const float*)d_in[2];
    const float* W2 = (const float*)d_in[3];
    const float* b2 = (const float*)d_in[4];
    float* out = (float*)d_out;

    int B = in_sizes[0] / NI;  // 262144
    int threads = 256;
    int blocks = (B + threads - 1) / threads;
    snn_kernel<<<blocks, threads, 0, stream>>>(x, W1, b1, W2, b2, out, B);
}